// Round 1
// baseline (758.884 us; speedup 1.0000x reference)
//
#include <hip/hip_runtime.h>

// out[M,128] = A[M,128] @ W[128,128] (+ bias[128] if bias != nullptr)
// Block = 256 threads. W staged in LDS (64 KB), A staged 16 rows at a time.
// Thread t computes column j = t&127 for rows {row0 + 2*i + (t>>7)}.
__global__ __launch_bounds__(256) void gemm_128(
    const float* __restrict__ A, const float* __restrict__ W,
    const float* __restrict__ bias, float* __restrict__ C, int M) {
  __shared__ float sW[128 * 128];
  __shared__ float sA[16 * 128];
  for (int i = threadIdx.x; i < 128 * 128; i += 256) sW[i] = W[i];
  __syncthreads();

  const int j  = threadIdx.x & 127;
  const int rh = threadIdx.x >> 7;  // 0 or 1, wave-uniform
  const float bj = bias ? bias[j] : 0.0f;
  const int ntile = (M + 15) >> 4;

  for (int tile = blockIdx.x; tile < ntile; tile += gridDim.x) {
    const int row0 = tile << 4;
    __syncthreads();  // protect sA against previous-iteration readers
    for (int i = threadIdx.x; i < 16 * 128; i += 256) {
      const int r = row0 + (i >> 7);
      sA[i] = (r < M) ? A[(size_t)r * 128 + (i & 127)] : 0.0f;
    }
    __syncthreads();

    float acc[8];
#pragma unroll
    for (int t = 0; t < 8; ++t) acc[t] = 0.0f;
#pragma unroll 4
    for (int k = 0; k < 128; ++k) {
      const float w = sW[k * 128 + j];          // stride-1 across lanes: 2-way (free)
#pragma unroll
      for (int t = 0; t < 8; ++t)
        acc[t] += sA[(t * 2 + rh) * 128 + k] * w;  // broadcast (wave-uniform addr)
    }
#pragma unroll
    for (int t = 0; t < 8; ++t) {
      const int r = row0 + t * 2 + rh;
      if (r < M) C[(size_t)r * 128 + j] = acc[t] + bj;
    }
  }
}

// One wave (64 lanes) per edge; 2 dims per lane (float2).
__global__ __launch_bounds__(256) void edge_kernel(
    const int* __restrict__ edge_sub, const int* __restrict__ edge_rel,
    const int* __restrict__ edge_obj, const int* __restrict__ r_idx,
    const int* __restrict__ q_rel,
    const float* __restrict__ hidden, const float* __restrict__ rela,
    const float* __restrict__ Hws, const float* __restrict__ Rwr,
    const float* __restrict__ Rwqr, const float* __restrict__ wa_w,
    const float* __restrict__ wa_b_p,
    float* __restrict__ agg, int E) {
  const int gid = blockIdx.x * blockDim.x + threadIdx.x;
  const int e = gid >> 6;
  if (e >= E) return;
  const int lane = threadIdx.x & 63;
  const int d = lane * 2;

  const int s  = edge_sub[e];
  const int r  = edge_rel[e];
  const int o  = edge_obj[e];
  const int qr = q_rel[r_idx[e]];

  const float2 a = *(const float2*)(Hws  + (size_t)s  * 128 + d);
  const float2 b = *(const float2*)(Rwr  + (size_t)r  * 128 + d);
  const float2 c = *(const float2*)(Rwqr + (size_t)qr * 128 + d);
  const float2 w = *(const float2*)(wa_w + d);

  const float p0 = fmaxf(a.x + b.x + c.x, 0.0f);
  const float p1 = fmaxf(a.y + b.y + c.y, 0.0f);
  float part = p0 * w.x + p1 * w.y;
#pragma unroll
  for (int off = 32; off; off >>= 1) part += __shfl_xor(part, off);

  const float alpha = 1.0f / (1.0f + __expf(-(part + wa_b_p[0])));

  const float2 hs = *(const float2*)(hidden + (size_t)s * 128 + d);
  const float2 hr = *(const float2*)(rela   + (size_t)r * 128 + d);
  atomicAdd(agg + (size_t)o * 128 + d,     alpha * hs.x * hr.x);
  atomicAdd(agg + (size_t)o * 128 + d + 1, alpha * hs.y * hr.y);
}

extern "C" void kernel_launch(void* const* d_in, const int* in_sizes, int n_in,
                              void* d_out, int out_size, void* d_ws, size_t ws_size,
                              hipStream_t stream) {
  // setup_inputs order:
  // 0 q_sub, 1 q_rel, 2 r_idx, 3 hidden, 4 edge_sub, 5 edge_rel, 6 edge_obj,
  // 7 n_node, 8 rela_embed, 9 Ws, 10 Wr, 11 Wqr_w, 12 Wqr_b, 13 wa_w, 14 wa_b, 15 Wh
  const int*   q_rel    = (const int*)d_in[1];
  const int*   r_idx    = (const int*)d_in[2];
  const float* hidden   = (const float*)d_in[3];
  const int*   edge_sub = (const int*)d_in[4];
  const int*   edge_rel = (const int*)d_in[5];
  const int*   edge_obj = (const int*)d_in[6];
  const float* rela     = (const float*)d_in[8];
  const float* Ws       = (const float*)d_in[9];
  const float* Wr       = (const float*)d_in[10];
  const float* Wqr_w    = (const float*)d_in[11];
  const float* Wqr_b    = (const float*)d_in[12];
  const float* wa_w     = (const float*)d_in[13];
  const float* wa_b     = (const float*)d_in[14];
  const float* Wh       = (const float*)d_in[15];

  const int E      = in_sizes[2];        // 600000
  const int n_node = in_sizes[3] / 128;  // 50000
  const int n_rel  = in_sizes[8] / 128;  // 475
  float* out = (float*)d_out;

  // Workspace layout (f32): agg[n_node*128] | Hws[n_node*128] | Rwr[n_rel*128] | Rwqr[n_rel*128]
  char* ws = (char*)d_ws;
  float* agg  = (float*)ws;
  float* Hws  = (float*)(ws + (size_t)n_node * 128 * sizeof(float));
  float* Rwr  = (float*)(ws + (size_t)n_node * 128 * sizeof(float) * 2);
  float* Rwqr = Rwr + (size_t)n_rel * 128;

  hipMemsetAsync(agg, 0, (size_t)n_node * 128 * sizeof(float), stream);

  const int rel_tiles = (n_rel + 15) / 16;
  gemm_128<<<dim3(rel_tiles), dim3(256), 0, stream>>>(rela, Wr, nullptr, Rwr, n_rel);
  gemm_128<<<dim3(rel_tiles), dim3(256), 0, stream>>>(rela, Wqr_w, Wqr_b, Rwqr, n_rel);
  gemm_128<<<dim3(1024), dim3(256), 0, stream>>>(hidden, Ws, nullptr, Hws, n_node);

  const int eblocks = (int)(((size_t)E * 64 + 255) / 256);
  edge_kernel<<<dim3(eblocks), dim3(256), 0, stream>>>(
      edge_sub, edge_rel, edge_obj, r_idx, q_rel,
      hidden, rela, Hws, Rwr, Rwqr, wa_w, wa_b, agg, E);

  gemm_128<<<dim3(1024), dim3(256), 0, stream>>>(agg, Wh, nullptr, out, n_node);
}

// Round 2
// 511.718 us; speedup vs baseline: 1.4830x; 1.4830x over previous
//
#include <hip/hip_runtime.h>

// ---------------------------------------------------------------------------
// C[M,128] = A[M,128] @ W[128,128] (+ bias). 4x4 register blocking.
// Block 256 threads; tile 32 rows x 128 cols. W (64KB) + A-tile (16KB) in LDS.
// tx = t&31 -> col quad (col0 = 4*tx), ty = t>>5 -> row quad (r0 = 4*ty).
// ---------------------------------------------------------------------------
__global__ __launch_bounds__(256) void gemm_tile(
    const float* __restrict__ A, const float* __restrict__ W,
    const float* __restrict__ bias, float* __restrict__ C, int M) {
  __shared__ float sW[128 * 128];  // 64 KB
  __shared__ float sA[32 * 128];   // 16 KB
  for (int i = threadIdx.x; i < 128 * 128; i += 256) sW[i] = W[i];

  const int tx = threadIdx.x & 31;   // col quad
  const int ty = threadIdx.x >> 5;   // row quad
  const int col0 = tx * 4;
  const int ntile = (M + 31) >> 5;

  float4 bj = make_float4(0.f, 0.f, 0.f, 0.f);
  if (bias) bj = *(const float4*)(bias + col0);

  for (int tile = blockIdx.x; tile < ntile; tile += gridDim.x) {
    const int row_base = tile << 5;
    __syncthreads();  // sW ready (first iter) / protect sA from prev readers
    for (int i = threadIdx.x; i < 32 * 128; i += 256) {
      const int r = row_base + (i >> 7);
      sA[i] = (r < M) ? A[(size_t)r * 128 + (i & 127)] : 0.0f;
    }
    __syncthreads();

    float acc[4][4];
#pragma unroll
    for (int i = 0; i < 4; ++i)
#pragma unroll
      for (int j = 0; j < 4; ++j) acc[i][j] = 0.0f;

#pragma unroll 2
    for (int k4 = 0; k4 < 128; k4 += 4) {
      float4 a[4], w[4];
#pragma unroll
      for (int i = 0; i < 4; ++i)
        a[i] = *(const float4*)&sA[(ty * 4 + i) * 128 + k4];   // broadcast
#pragma unroll
      for (int kk = 0; kk < 4; ++kk)
        w[kk] = *(const float4*)&sW[(k4 + kk) * 128 + col0];   // stride-1 b128
#pragma unroll
      for (int i = 0; i < 4; ++i) {
        acc[i][0] += a[i].x * w[0].x + a[i].y * w[1].x + a[i].z * w[2].x + a[i].w * w[3].x;
        acc[i][1] += a[i].x * w[0].y + a[i].y * w[1].y + a[i].z * w[2].y + a[i].w * w[3].y;
        acc[i][2] += a[i].x * w[0].z + a[i].y * w[1].z + a[i].z * w[2].z + a[i].w * w[3].z;
        acc[i][3] += a[i].x * w[0].w + a[i].y * w[1].w + a[i].z * w[2].w + a[i].w * w[3].w;
      }
    }

#pragma unroll
    for (int i = 0; i < 4; ++i) {
      const int r = row_base + ty * 4 + i;
      if (r < M) {
        float4 o = make_float4(acc[i][0] + bj.x, acc[i][1] + bj.y,
                               acc[i][2] + bj.z, acc[i][3] + bj.w);
        *(float4*)&C[(size_t)r * 128 + col0] = o;
      }
    }
  }
}

// ---------------------------------------------------------------------------
// Counting sort of edges by edge_obj
// ---------------------------------------------------------------------------
__global__ __launch_bounds__(256) void hist_kernel(const int* __restrict__ edge_obj,
                                                   int* __restrict__ deg, int E) {
  for (int i = blockIdx.x * blockDim.x + threadIdx.x; i < E; i += gridDim.x * blockDim.x)
    atomicAdd(deg + edge_obj[i], 1);
}

// single block, 1024 threads: exclusive scan deg[0..n) -> off[0..n], cursor copy
__global__ __launch_bounds__(1024) void scan_kernel(const int* __restrict__ deg,
                                                    int* __restrict__ off,
                                                    int* __restrict__ cursor, int n) {
  const int t = threadIdx.x;
  const int CH = (n + 1023) / 1024;
  const int lo = t * CH;
  const int hi = min(lo + CH, n);
  int sum = 0;
  for (int i = lo; i < hi; ++i) sum += deg[i];
  __shared__ int part[1024];
  part[t] = sum;
  __syncthreads();
  for (int o = 1; o < 1024; o <<= 1) {
    int v = (t >= o) ? part[t - o] : 0;
    __syncthreads();
    part[t] += v;
    __syncthreads();
  }
  int run = part[t] - sum;  // exclusive prefix of this chunk
  for (int i = lo; i < hi; ++i) {
    int d = deg[i];
    off[i] = run;
    cursor[i] = run;
    run += d;
  }
  if (t == 1023) off[n] = part[1023];
}

__global__ __launch_bounds__(256) void scatter_kernel(const int* __restrict__ edge_obj,
                                                      int* __restrict__ cursor,
                                                      int* __restrict__ se, int E) {
  for (int i = blockIdx.x * blockDim.x + threadIdx.x; i < E; i += gridDim.x * blockDim.x) {
    const int p = atomicAdd(cursor + edge_obj[i], 1);
    se[p] = i;
  }
}

// ---------------------------------------------------------------------------
// Per-node gather-reduce. One wave per node, lane owns dims {2l, 2l+1}.
// For each edge of the node: alpha = sigmoid(wa . relu(Hws[s]+Rwr[r]+Rwqr[qr]) + b),
// acc += alpha * hidden[s] * rela[r].  Deterministic, atomic-free.
// ---------------------------------------------------------------------------
__global__ __launch_bounds__(256) void reduce_kernel(
    const int* __restrict__ se, const int* __restrict__ off,
    const int* __restrict__ edge_sub, const int* __restrict__ edge_rel,
    const int* __restrict__ r_idx, const int* __restrict__ q_rel,
    const float* __restrict__ hidden, const float* __restrict__ rela,
    const float* __restrict__ Hws, const float* __restrict__ Rwr,
    const float* __restrict__ Rwqr, const float* __restrict__ wa_w,
    const float* __restrict__ wa_b_p,
    float* __restrict__ agg, int n_node) {
  const int wave = (blockIdx.x * blockDim.x + threadIdx.x) >> 6;
  if (wave >= n_node) return;
  const int lane = threadIdx.x & 63;
  const int d = lane * 2;

  const float2 w2 = *(const float2*)(wa_w + d);
  const float wab = wa_b_p[0];
  const int start = off[wave];
  const int end = off[wave + 1];

  float acc0 = 0.0f, acc1 = 0.0f;

  for (int c = start; c < end; c += 64) {
    const int idx = c + lane;
    int s = 0, r = 0, qr = 0;
    if (idx < end) {
      const int e = se[idx];
      s = edge_sub[e];
      r = edge_rel[e];
      qr = q_rel[r_idx[e]];
    }
    const int cnt = min(end - c, 64);
    for (int j = 0; j < cnt; ++j) {
      const int sj = __shfl(s, j);
      const int rj = __shfl(r, j);
      const int qj = __shfl(qr, j);

      const float2 a = *(const float2*)(Hws  + (size_t)sj * 128 + d);
      const float2 b = *(const float2*)(Rwr  + (size_t)rj * 128 + d);
      const float2 cq = *(const float2*)(Rwqr + (size_t)qj * 128 + d);
      const float2 hs = *(const float2*)(hidden + (size_t)sj * 128 + d);
      const float2 hr = *(const float2*)(rela   + (size_t)rj * 128 + d);

      const float p0 = fmaxf(a.x + b.x + cq.x, 0.0f);
      const float p1 = fmaxf(a.y + b.y + cq.y, 0.0f);
      float part = p0 * w2.x + p1 * w2.y;
#pragma unroll
      for (int o = 32; o; o >>= 1) part += __shfl_xor(part, o);
      const float alpha = 1.0f / (1.0f + __expf(-(part + wab)));

      acc0 += alpha * hs.x * hr.x;
      acc1 += alpha * hs.y * hr.y;
    }
  }

  float2 o2 = make_float2(acc0, acc1);
  *(float2*)(agg + (size_t)wave * 128 + d) = o2;
}

// ---------------------------------------------------------------------------
extern "C" void kernel_launch(void* const* d_in, const int* in_sizes, int n_in,
                              void* d_out, int out_size, void* d_ws, size_t ws_size,
                              hipStream_t stream) {
  // 0 q_sub, 1 q_rel, 2 r_idx, 3 hidden, 4 edge_sub, 5 edge_rel, 6 edge_obj,
  // 7 n_node, 8 rela_embed, 9 Ws, 10 Wr, 11 Wqr_w, 12 Wqr_b, 13 wa_w, 14 wa_b, 15 Wh
  const int*   q_rel    = (const int*)d_in[1];
  const int*   r_idx    = (const int*)d_in[2];
  const float* hidden   = (const float*)d_in[3];
  const int*   edge_sub = (const int*)d_in[4];
  const int*   edge_rel = (const int*)d_in[5];
  const int*   edge_obj = (const int*)d_in[6];
  const float* rela     = (const float*)d_in[8];
  const float* Ws       = (const float*)d_in[9];
  const float* Wr       = (const float*)d_in[10];
  const float* Wqr_w    = (const float*)d_in[11];
  const float* Wqr_b    = (const float*)d_in[12];
  const float* wa_w     = (const float*)d_in[13];
  const float* wa_b     = (const float*)d_in[14];
  const float* Wh       = (const float*)d_in[15];

  const int E      = in_sizes[2];        // 600000
  const int n_node = in_sizes[3] / 128;  // 50000
  const int n_rel  = in_sizes[8] / 128;  // 475
  float* out = (float*)d_out;

  // workspace layout (all 512B-aligned)
  auto align512 = [](size_t x) { return (x + 511) & ~(size_t)511; };
  char* ws = (char*)d_ws;
  size_t off_b = 0;
  float* Hws  = (float*)(ws + off_b); off_b += align512((size_t)n_node * 128 * 4);
  float* agg  = (float*)(ws + off_b); off_b += align512((size_t)n_node * 128 * 4);
  float* Rwr  = (float*)(ws + off_b); off_b += align512((size_t)n_rel * 128 * 4);
  float* Rwqr = (float*)(ws + off_b); off_b += align512((size_t)n_rel * 128 * 4);
  int*   deg  = (int*)(ws + off_b);   off_b += align512((size_t)n_node * 4);
  int*   offs = (int*)(ws + off_b);   off_b += align512((size_t)(n_node + 1) * 4);
  int*   curs = (int*)(ws + off_b);   off_b += align512((size_t)n_node * 4);
  int*   se   = (int*)(ws + off_b);   off_b += align512((size_t)E * 4);

  // --- counting sort by edge_obj ---
  hipMemsetAsync(deg, 0, (size_t)n_node * 4, stream);
  hist_kernel<<<dim3(1024), dim3(256), 0, stream>>>(edge_obj, deg, E);
  scan_kernel<<<dim3(1), dim3(1024), 0, stream>>>(deg, offs, curs, n_node);
  scatter_kernel<<<dim3(1024), dim3(256), 0, stream>>>(edge_obj, curs, se, E);

  // --- precompute projections ---
  const int rel_tiles = (n_rel + 31) / 32;
  gemm_tile<<<dim3(rel_tiles), dim3(256), 0, stream>>>(rela, Wr, nullptr, Rwr, n_rel);
  gemm_tile<<<dim3(rel_tiles), dim3(256), 0, stream>>>(rela, Wqr_w, Wqr_b, Rwqr, n_rel);
  const int node_tiles = (n_node + 31) / 32;
  gemm_tile<<<dim3(node_tiles), dim3(256), 0, stream>>>(hidden, Ws, nullptr, Hws, n_node);

  // --- fused per-node attention + aggregation (atomic-free) ---
  const int rblocks = (n_node * 64 + 255) / 256;
  reduce_kernel<<<dim3(rblocks), dim3(256), 0, stream>>>(
      se, offs, edge_sub, edge_rel, r_idx, q_rel,
      hidden, rela, Hws, Rwr, Rwqr, wa_w, wa_b, agg, n_node);

  // --- final projection ---
  gemm_tile<<<dim3(node_tiles), dim3(256), 0, stream>>>(agg, Wh, nullptr, out, n_node);
}

// Round 5
// 375.357 us; speedup vs baseline: 2.0218x; 1.3633x over previous
//
#include <hip/hip_runtime.h>

typedef short bf16x8 __attribute__((ext_vector_type(8)));
typedef float f32x4 __attribute__((ext_vector_type(4)));

__device__ __forceinline__ short f2bf(float x) {  // round-to-nearest-even
  union { float f; unsigned int u; } v; v.f = x;
  unsigned int r = v.u + 0x7FFFu + ((v.u >> 16) & 1u);
  return (short)(r >> 16);
}
__device__ __forceinline__ float bflo(unsigned int w) {
  union { unsigned int u; float f; } v; v.u = w << 16; return v.f;
}
__device__ __forceinline__ float bfhi(unsigned int w) {
  union { unsigned int u; float f; } v; v.u = w & 0xFFFF0000u; return v.f;
}

// ---------------------------------------------------------------------------
// f32 rows -> bf16 rows with dst leading-dim (for Hcat/Rcat interleaves)
// ---------------------------------------------------------------------------
__global__ __launch_bounds__(256) void conv_rows(const float* __restrict__ src,
                                                 short* __restrict__ dst,
                                                 int n_rows, int dst_ld) {
  const int total = n_rows * 32;  // float4 groups per 128-row
  for (int i = blockIdx.x * blockDim.x + threadIdx.x; i < total;
       i += gridDim.x * blockDim.x) {
    const int row = i >> 5, c4 = (i & 31) * 4;
    const float4 v = *(const float4*)(src + (size_t)row * 128 + c4);
    short4 o = make_short4(f2bf(v.x), f2bf(v.y), f2bf(v.z), f2bf(v.w));
    *(short4*)(dst + (size_t)row * dst_ld + c4) = o;
  }
}

// ---------------------------------------------------------------------------
// Weights f32[128][128] -> bf16 transposed+k-grouped: Wt8[(k>>3)*1024 + col*8 + (k&7)]
// (B-frag for mfma = 16B contiguous read, conflict-free in LDS)
// ---------------------------------------------------------------------------
__global__ __launch_bounds__(256) void conv_w(
    const float* __restrict__ W0, const float* __restrict__ W1,
    const float* __restrict__ W2, const float* __restrict__ W3,
    short* __restrict__ o0, short* __restrict__ o1,
    short* __restrict__ o2, short* __restrict__ o3) {
  const int id = blockIdx.x * 256 + threadIdx.x;  // 0..65535
  const int m = id >> 14, e = id & 16383;
  const int k = e >> 7, c = e & 127;
  const float* W = (m == 0) ? W0 : (m == 1) ? W1 : (m == 2) ? W2 : W3;
  short* o = (m == 0) ? o0 : (m == 1) ? o1 : (m == 2) ? o2 : o3;
  o[(k >> 3) * 1024 + c * 8 + (k & 7)] = f2bf(W[e]);
}

// ---------------------------------------------------------------------------
// C[M,128] = A[M,128] @ W[128,128] (+bias) via mfma_f32_16x16x32_bf16.
// Block = 256 thr = 4 waves; tile 64 rows. Wave w: rows [64b+16w, +16).
// A: bf16 (lda elems) or f32 (converted in-reg). C: bf16 or f32, ldc/c_off.
// Wt8: pre-transposed bf16 weight (see conv_w). Staged to LDS (32KB copy).
// ---------------------------------------------------------------------------
template <bool A_BF16, bool C_BF16, bool HAS_BIAS>
__global__ __launch_bounds__(256) void gemm_mfma(
    const void* __restrict__ Av, int lda, const short* __restrict__ Wt8,
    const float* __restrict__ bias, void* __restrict__ Cv, int ldc, int c_off,
    int M) {
  __shared__ short sW[16384];
  for (int i = threadIdx.x; i < 2048; i += 256)
    ((bf16x8*)sW)[i] = ((const bf16x8*)Wt8)[i];
  __syncthreads();

  const int wv = threadIdx.x >> 6;
  const int l = threadIdx.x & 63;
  const int row = blockIdx.x * 64 + wv * 16 + (l & 15);
  const int kb = (l >> 4) * 8;
  const bool rvalid = row < M;

  bf16x8 a[4];
  if (A_BF16) {
    const short* A = (const short*)Av;
#pragma unroll
    for (int kk = 0; kk < 4; ++kk) {
      bf16x8 t = {0, 0, 0, 0, 0, 0, 0, 0};
      if (rvalid) t = *(const bf16x8*)(A + (size_t)row * lda + kb + 32 * kk);
      a[kk] = t;
    }
  } else {
    const float* A = (const float*)Av;
#pragma unroll
    for (int kk = 0; kk < 4; ++kk) {
      bf16x8 t = {0, 0, 0, 0, 0, 0, 0, 0};
      if (rvalid) {
        const f32x4 lo = *(const f32x4*)(A + (size_t)row * lda + kb + 32 * kk);
        const f32x4 hi = *(const f32x4*)(A + (size_t)row * lda + kb + 32 * kk + 4);
        t[0] = f2bf(lo[0]); t[1] = f2bf(lo[1]); t[2] = f2bf(lo[2]); t[3] = f2bf(lo[3]);
        t[4] = f2bf(hi[0]); t[5] = f2bf(hi[1]); t[6] = f2bf(hi[2]); t[7] = f2bf(hi[3]);
      }
      a[kk] = t;
    }
  }

  f32x4 acc[8];
#pragma unroll
  for (int n = 0; n < 8; ++n) acc[n] = (f32x4){0.f, 0.f, 0.f, 0.f};

#pragma unroll
  for (int n = 0; n < 8; ++n) {
#pragma unroll
    for (int kk = 0; kk < 4; ++kk) {
      const int kg = 4 * kk + (l >> 4);
      const bf16x8 b = *(const bf16x8*)(sW + kg * 1024 + (16 * n + (l & 15)) * 8);
      acc[n] = __builtin_amdgcn_mfma_f32_16x16x32_bf16(a[kk], b, acc[n], 0, 0, 0);
    }
  }

  const int orow_base = blockIdx.x * 64 + wv * 16 + (l >> 4) * 4;
#pragma unroll
  for (int n = 0; n < 8; ++n) {
    const int col = 16 * n + (l & 15);
    const float badd = HAS_BIAS ? bias[col] : 0.0f;
#pragma unroll
    for (int r4 = 0; r4 < 4; ++r4) {
      const int orow = orow_base + r4;
      if (orow < M) {
        const float v = acc[n][r4] + badd;
        if (C_BF16)
          ((short*)Cv)[(size_t)orow * ldc + c_off + col] = f2bf(v);
        else
          ((float*)Cv)[(size_t)orow * ldc + c_off + col] = v;
      }
    }
  }
}

// ---------------------------------------------------------------------------
// Counting sort by edge_obj; scatter emits pre-gathered (s, r*512+qr)
// ---------------------------------------------------------------------------
__global__ __launch_bounds__(256) void hist_kernel(const int* __restrict__ edge_obj,
                                                   int* __restrict__ deg, int E) {
  for (int i = blockIdx.x * blockDim.x + threadIdx.x; i < E; i += gridDim.x * blockDim.x)
    atomicAdd(deg + edge_obj[i], 1);
}

__global__ __launch_bounds__(1024) void scan_kernel(const int* __restrict__ deg,
                                                    int* __restrict__ off,
                                                    int* __restrict__ cursor, int n) {
  const int t = threadIdx.x;
  const int CH = (n + 1023) / 1024;
  const int lo = t * CH;
  const int hi = min(lo + CH, n);
  int sum = 0;
  for (int i = lo; i < hi; ++i) sum += deg[i];
  __shared__ int part[1024];
  part[t] = sum;
  __syncthreads();
  for (int o = 1; o < 1024; o <<= 1) {
    int v = (t >= o) ? part[t - o] : 0;
    __syncthreads();
    part[t] += v;
    __syncthreads();
  }
  int run = part[t] - sum;
  for (int i = lo; i < hi; ++i) {
    int d = deg[i];
    off[i] = run;
    cursor[i] = run;
    run += d;
  }
  if (t == 1023) off[n] = part[1023];
}

__global__ __launch_bounds__(256) void scatter_kernel(
    const int* __restrict__ edge_obj, const int* __restrict__ edge_sub,
    const int* __restrict__ edge_rel, const int* __restrict__ r_idx,
    const int* __restrict__ q_rel, int* __restrict__ cursor,
    int* __restrict__ ss, int* __restrict__ srq, int E) {
  for (int i = blockIdx.x * blockDim.x + threadIdx.x; i < E; i += gridDim.x * blockDim.x) {
    const int p = atomicAdd(cursor + edge_obj[i], 1);
    ss[p] = edge_sub[i];
    srq[p] = (edge_rel[i] << 9) | q_rel[r_idx[i]];
  }
}

// ---------------------------------------------------------------------------
// Per-node gather-reduce, bf16. One wave per node; 4 edges x 16 lanes;
// lane owns dims [8*(l&15), +8). Hcat=[hidden||Hws], Rcat=[rela||Rwr] bf16.
// ---------------------------------------------------------------------------
__global__ __launch_bounds__(256) void reduce_bf16(
    const int* __restrict__ ss, const int* __restrict__ srq,
    const int* __restrict__ offs, const short* __restrict__ Hcat,
    const short* __restrict__ Rcat, const short* __restrict__ Rwqrt,
    const float* __restrict__ wa_w, const float* __restrict__ wa_b_p,
    float* __restrict__ agg, int n_node) {
  const int node = (blockIdx.x * blockDim.x + threadIdx.x) >> 6;
  if (node >= n_node) return;
  const int l = threadIdx.x & 63;
  const int g = l >> 4;
  const int d0 = (l & 15) * 8;

  float wa8[8];
  *(float4*)(wa8) = *(const float4*)(wa_w + d0);
  *(float4*)(wa8 + 4) = *(const float4*)(wa_w + d0 + 4);
  const float wab = wa_b_p[0];

  const int start = offs[node], end = offs[node + 1];
  float acc[8];
#pragma unroll
  for (int i = 0; i < 8; ++i) acc[i] = 0.0f;

  for (int base = start; base < end; base += 64) {
    const int cnt = min(end - base, 64);
    int s_all = 0, rq_all = 0;
    if (l < cnt) { s_all = ss[base + l]; rq_all = srq[base + l]; }
    for (int c = 0; c < cnt; c += 4) {
      const int src = c + g;
      const bool valid = src < cnt;
      const int sv = __shfl(s_all, src);
      const int rqv = __shfl(rq_all, src);
      const int rv = rqv >> 9, qv = rqv & 511;

      const bf16x8 hws = *(const bf16x8*)(Hcat + ((size_t)sv << 8) + 128 + d0);
      const bf16x8 rwr = *(const bf16x8*)(Rcat + ((size_t)rv << 8) + 128 + d0);
      const bf16x8 rqr = *(const bf16x8*)(Rwqrt + ((size_t)qv << 7) + d0);
      const bf16x8 hs = *(const bf16x8*)(Hcat + ((size_t)sv << 8) + d0);
      const bf16x8 hr = *(const bf16x8*)(Rcat + ((size_t)rv << 8) + d0);

      const unsigned int* uw = (const unsigned int*)&hws;
      const unsigned int* ur = (const unsigned int*)&rwr;
      const unsigned int* uq = (const unsigned int*)&rqr;
      const unsigned int* uh = (const unsigned int*)&hs;
      const unsigned int* ug = (const unsigned int*)&hr;

      float part = 0.0f;
      float hsf[8], hrf[8];
#pragma unroll
      for (int i = 0; i < 4; ++i) {
        const float p0 = fmaxf(bflo(uw[i]) + bflo(ur[i]) + bflo(uq[i]), 0.0f);
        const float p1 = fmaxf(bfhi(uw[i]) + bfhi(ur[i]) + bfhi(uq[i]), 0.0f);
        part += p0 * wa8[2 * i] + p1 * wa8[2 * i + 1];
        hsf[2 * i] = bflo(uh[i]); hsf[2 * i + 1] = bfhi(uh[i]);
        hrf[2 * i] = bflo(ug[i]); hrf[2 * i + 1] = bfhi(ug[i]);
      }
      part += __shfl_xor(part, 1);
      part += __shfl_xor(part, 2);
      part += __shfl_xor(part, 4);
      part += __shfl_xor(part, 8);
      const float alpha = 1.0f / (1.0f + __expf(-(part + wab)));
      if (valid) {
#pragma unroll
        for (int i = 0; i < 8; ++i) acc[i] += alpha * hsf[i] * hrf[i];
      }
    }
  }
#pragma unroll
  for (int i = 0; i < 8; ++i) {
    acc[i] += __shfl_xor(acc[i], 16);
    acc[i] += __shfl_xor(acc[i], 32);
  }
  if (l < 16) {
    float4 o0 = make_float4(acc[0], acc[1], acc[2], acc[3]);
    float4 o1 = make_float4(acc[4], acc[5], acc[6], acc[7]);
    *(float4*)(agg + (size_t)node * 128 + d0) = o0;
    *(float4*)(agg + (size_t)node * 128 + d0 + 4) = o1;
  }
}

// ---------------------------------------------------------------------------
extern "C" void kernel_launch(void* const* d_in, const int* in_sizes, int n_in,
                              void* d_out, int out_size, void* d_ws, size_t ws_size,
                              hipStream_t stream) {
  const int* q_rel = (const int*)d_in[1];
  const int* r_idx = (const int*)d_in[2];
  const float* hidden = (const float*)d_in[3];
  const int* edge_sub = (const int*)d_in[4];
  const int* edge_rel = (const int*)d_in[5];
  const int* edge_obj = (const int*)d_in[6];
  const float* rela = (const float*)d_in[8];
  const float* Ws = (const float*)d_in[9];
  const float* Wr = (const float*)d_in[10];
  const float* Wqr_w = (const float*)d_in[11];
  const float* Wqr_b = (const float*)d_in[12];
  const float* wa_w = (const float*)d_in[13];
  const float* wa_b = (const float*)d_in[14];
  const float* Wh = (const float*)d_in[15];

  const int E = in_sizes[2];
  const int n_node = in_sizes[3] / 128;
  const int n_rel = in_sizes[8] / 128;
  float* out = (float*)d_out;

  auto al = [](size_t x) { return (x + 511) & ~(size_t)511; };
  char* ws = (char*)d_ws;
  size_t o = 0;
  short* Hcat = (short*)(ws + o);  o += al((size_t)n_node * 256 * 2);
  float* agg  = (float*)(ws + o);  o += al((size_t)n_node * 128 * 4);
  short* Rcat = (short*)(ws + o);  o += al((size_t)n_rel * 256 * 2);
  short* Rwqrt = (short*)(ws + o); o += al((size_t)n_rel * 128 * 2);
  short* Wst8 = (short*)(ws + o);  o += al(16384 * 2);
  short* Wrt8 = (short*)(ws + o);  o += al(16384 * 2);
  short* Wqrt8 = (short*)(ws + o); o += al(16384 * 2);
  short* Wht8 = (short*)(ws + o);  o += al(16384 * 2);
  int* deg = (int*)(ws + o);       o += al((size_t)n_node * 4);
  int* offs = (int*)(ws + o);      o += al((size_t)(n_node + 1) * 4);
  int* curs = (int*)(ws + o);      o += al((size_t)n_node * 4);
  int* ss = (int*)(ws + o);        o += al((size_t)E * 4);
  int* srq = (int*)(ws + o);       o += al((size_t)E * 4);

  // --- counting sort (independent of conversions) ---
  hipMemsetAsync(deg, 0, (size_t)n_node * 4, stream);
  hist_kernel<<<dim3(1024), dim3(256), 0, stream>>>(edge_obj, deg, E);
  scan_kernel<<<dim3(1), dim3(1024), 0, stream>>>(deg, offs, curs, n_node);
  scatter_kernel<<<dim3(1024), dim3(256), 0, stream>>>(
      edge_obj, edge_sub, edge_rel, r_idx, q_rel, curs, ss, srq, E);

  // --- bf16 conversions ---
  conv_w<<<dim3(256), dim3(256), 0, stream>>>(Ws, Wr, Wqr_w, Wh,
                                              Wst8, Wrt8, Wqrt8, Wht8);
  conv_rows<<<dim3(64), dim3(256), 0, stream>>>(rela, Rcat, n_rel, 256);
  conv_rows<<<dim3(2048), dim3(256), 0, stream>>>(hidden, Hcat, n_node, 256);

  // --- projections via MFMA ---
  const int rel_blocks = (n_rel + 63) / 64;
  const int node_blocks = (n_node + 63) / 64;
  gemm_mfma<true, true, false><<<dim3(rel_blocks), dim3(256), 0, stream>>>(
      Rcat, 256, Wrt8, nullptr, Rcat, 256, 128, n_rel);
  gemm_mfma<true, true, true><<<dim3(rel_blocks), dim3(256), 0, stream>>>(
      Rcat, 256, Wqrt8, Wqr_b, Rwqrt, 128, 0, n_rel);
  gemm_mfma<true, true, false><<<dim3(node_blocks), dim3(256), 0, stream>>>(
      Hcat, 256, Wst8, nullptr, Hcat, 256, 128, n_node);

  // --- fused attention + aggregation ---
  const int rblocks = (n_node * 64 + 255) / 256;
  reduce_bf16<<<dim3(rblocks), dim3(256), 0, stream>>>(
      ss, srq, offs, Hcat, Rcat, Rwqrt, wa_w, wa_b, agg, n_node);

  // --- final projection (A f32 converted in-register) ---
  gemm_mfma<false, false, false><<<dim3(node_blocks), dim3(256), 0, stream>>>(
      agg, 128, Wht8, nullptr, out, 128, 0, n_node);
}

// Round 6
// 274.644 us; speedup vs baseline: 2.7632x; 1.3667x over previous
//
#include <hip/hip_runtime.h>

typedef short bf16x8 __attribute__((ext_vector_type(8)));
typedef float f32x4 __attribute__((ext_vector_type(4)));

__device__ __forceinline__ short f2bf(float x) {  // round-to-nearest-even
  union { float f; unsigned int u; } v; v.f = x;
  unsigned int r = v.u + 0x7FFFu + ((v.u >> 16) & 1u);
  return (short)(r >> 16);
}
__device__ __forceinline__ float bflo(unsigned int w) {
  union { unsigned int u; float f; } v; v.u = w << 16; return v.f;
}
__device__ __forceinline__ float bfhi(unsigned int w) {
  union { unsigned int u; float f; } v; v.u = w & 0xFFFF0000u; return v.f;
}

// ---------------------------------------------------------------------------
// f32 rows -> bf16 rows with dst leading-dim (for Hcat/Rcat interleaves)
// ---------------------------------------------------------------------------
__global__ __launch_bounds__(256) void conv_rows(const float* __restrict__ src,
                                                 short* __restrict__ dst,
                                                 int n_rows, int dst_ld) {
  const int total = n_rows * 32;  // float4 groups per 128-row
  for (int i = blockIdx.x * blockDim.x + threadIdx.x; i < total;
       i += gridDim.x * blockDim.x) {
    const int row = i >> 5, c4 = (i & 31) * 4;
    const float4 v = *(const float4*)(src + (size_t)row * 128 + c4);
    short4 o = make_short4(f2bf(v.x), f2bf(v.y), f2bf(v.z), f2bf(v.w));
    *(short4*)(dst + (size_t)row * dst_ld + c4) = o;
  }
}

// ---------------------------------------------------------------------------
// Weights f32[128][128] -> bf16 transposed+k-grouped: Wt8[(k>>3)*1024 + col*8 + (k&7)]
// ---------------------------------------------------------------------------
__global__ __launch_bounds__(256) void conv_w(
    const float* __restrict__ W0, const float* __restrict__ W1,
    const float* __restrict__ W2, const float* __restrict__ W3,
    short* __restrict__ o0, short* __restrict__ o1,
    short* __restrict__ o2, short* __restrict__ o3) {
  const int id = blockIdx.x * 256 + threadIdx.x;  // 0..65535
  const int m = id >> 14, e = id & 16383;
  const int k = e >> 7, c = e & 127;
  const float* W = (m == 0) ? W0 : (m == 1) ? W1 : (m == 2) ? W2 : W3;
  short* o = (m == 0) ? o0 : (m == 1) ? o1 : (m == 2) ? o2 : o3;
  o[(k >> 3) * 1024 + c * 8 + (k & 7)] = f2bf(W[e]);
}

// ---------------------------------------------------------------------------
// C[M,128] = A[M,128] @ W[128,128] (+bias) via mfma_f32_16x16x32_bf16.
// ---------------------------------------------------------------------------
template <bool A_BF16, bool C_BF16, bool HAS_BIAS>
__global__ __launch_bounds__(256) void gemm_mfma(
    const void* __restrict__ Av, int lda, const short* __restrict__ Wt8,
    const float* __restrict__ bias, void* __restrict__ Cv, int ldc, int c_off,
    int M) {
  __shared__ short sW[16384];
  for (int i = threadIdx.x; i < 2048; i += 256)
    ((bf16x8*)sW)[i] = ((const bf16x8*)Wt8)[i];
  __syncthreads();

  const int wv = threadIdx.x >> 6;
  const int l = threadIdx.x & 63;
  const int row = blockIdx.x * 64 + wv * 16 + (l & 15);
  const int kb = (l >> 4) * 8;
  const bool rvalid = row < M;

  bf16x8 a[4];
  if (A_BF16) {
    const short* A = (const short*)Av;
#pragma unroll
    for (int kk = 0; kk < 4; ++kk) {
      bf16x8 t = {0, 0, 0, 0, 0, 0, 0, 0};
      if (rvalid) t = *(const bf16x8*)(A + (size_t)row * lda + kb + 32 * kk);
      a[kk] = t;
    }
  } else {
    const float* A = (const float*)Av;
#pragma unroll
    for (int kk = 0; kk < 4; ++kk) {
      bf16x8 t = {0, 0, 0, 0, 0, 0, 0, 0};
      if (rvalid) {
        const f32x4 lo = *(const f32x4*)(A + (size_t)row * lda + kb + 32 * kk);
        const f32x4 hi = *(const f32x4*)(A + (size_t)row * lda + kb + 32 * kk + 4);
        t[0] = f2bf(lo[0]); t[1] = f2bf(lo[1]); t[2] = f2bf(lo[2]); t[3] = f2bf(lo[3]);
        t[4] = f2bf(hi[0]); t[5] = f2bf(hi[1]); t[6] = f2bf(hi[2]); t[7] = f2bf(hi[3]);
      }
      a[kk] = t;
    }
  }

  f32x4 acc[8];
#pragma unroll
  for (int n = 0; n < 8; ++n) acc[n] = (f32x4){0.f, 0.f, 0.f, 0.f};

#pragma unroll
  for (int n = 0; n < 8; ++n) {
#pragma unroll
    for (int kk = 0; kk < 4; ++kk) {
      const int kg = 4 * kk + (l >> 4);
      const bf16x8 b = *(const bf16x8*)(sW + kg * 1024 + (16 * n + (l & 15)) * 8);
      acc[n] = __builtin_amdgcn_mfma_f32_16x16x32_bf16(a[kk], b, acc[n], 0, 0, 0);
    }
  }

  const int orow_base = blockIdx.x * 64 + wv * 16 + (l >> 4) * 4;
#pragma unroll
  for (int n = 0; n < 8; ++n) {
    const int col = 16 * n + (l & 15);
    const float badd = HAS_BIAS ? bias[col] : 0.0f;
#pragma unroll
    for (int r4 = 0; r4 < 4; ++r4) {
      const int orow = orow_base + r4;
      if (orow < M) {
        const float v = acc[n][r4] + badd;
        if (C_BF16)
          ((short*)Cv)[(size_t)orow * ldc + c_off + col] = f2bf(v);
        else
          ((float*)Cv)[(size_t)orow * ldc + c_off + col] = v;
      }
    }
  }
}

// ---------------------------------------------------------------------------
// Counting sort by edge_obj; hierarchical 3-pass scan (512 elems / block)
// ---------------------------------------------------------------------------
__global__ __launch_bounds__(256) void hist_kernel(const int* __restrict__ edge_obj,
                                                   int* __restrict__ deg, int E) {
  for (int i = blockIdx.x * blockDim.x + threadIdx.x; i < E; i += gridDim.x * blockDim.x)
    atomicAdd(deg + edge_obj[i], 1);
}

__global__ __launch_bounds__(256) void scan_pass1(const int* __restrict__ deg,
                                                  int* __restrict__ bsum, int n) {
  const int b = blockIdx.x, t = threadIdx.x;
  const int i0 = b * 512 + t, i1 = i0 + 256;
  int v = 0;
  if (i0 < n) v += deg[i0];
  if (i1 < n) v += deg[i1];
  __shared__ int s[256];
  s[t] = v;
  __syncthreads();
  for (int o = 128; o > 0; o >>= 1) {
    if (t < o) s[t] += s[t + o];
    __syncthreads();
  }
  if (t == 0) bsum[b] = s[0];
}

// single block: exclusive scan of bsum[nb] -> bbase; writes off[n] = total
__global__ __launch_bounds__(1024) void scan_pass2(const int* __restrict__ bsum,
                                                   int* __restrict__ bbase,
                                                   int* __restrict__ off,
                                                   int nb, int n) {
  const int t = threadIdx.x;
  __shared__ int s[1024];
  const int v = (t < nb) ? bsum[t] : 0;
  s[t] = v;
  __syncthreads();
  for (int o = 1; o < 1024; o <<= 1) {
    const int a = (t >= o) ? s[t - o] : 0;
    __syncthreads();
    s[t] += a;
    __syncthreads();
  }
  if (t < nb) bbase[t] = s[t] - v;  // exclusive
  if (t == 1023) off[n] = s[1023];  // grand total (= E)
}

__global__ __launch_bounds__(256) void scan_pass3(const int* __restrict__ deg,
                                                  const int* __restrict__ bbase,
                                                  int* __restrict__ off,
                                                  int* __restrict__ cursor, int n) {
  const int b = blockIdx.x, t = threadIdx.x;
  const int i0 = b * 512 + t, i1 = i0 + 256;
  const int d0 = (i0 < n) ? deg[i0] : 0;
  const int d1 = (i1 < n) ? deg[i1] : 0;
  __shared__ int s[512];
  s[t] = d0;
  s[t + 256] = d1;
  __syncthreads();
  for (int o = 1; o < 512; o <<= 1) {
    const int a0 = (t >= o) ? s[t - o] : 0;
    const int a1 = (t + 256 >= o) ? s[t + 256 - o] : 0;
    __syncthreads();
    s[t] += a0;
    s[t + 256] += a1;
    __syncthreads();
  }
  const int base = bbase[b];
  if (i0 < n) { const int e = base + s[t] - d0;       off[i0] = e; cursor[i0] = e; }
  if (i1 < n) { const int e = base + s[t + 256] - d1; off[i1] = e; cursor[i1] = e; }
}

__global__ __launch_bounds__(256) void scatter_kernel(
    const int* __restrict__ edge_obj, const int* __restrict__ edge_sub,
    const int* __restrict__ edge_rel, const int* __restrict__ r_idx,
    const int* __restrict__ q_rel, int* __restrict__ cursor,
    int* __restrict__ ss, int* __restrict__ srq, int E) {
  for (int i = blockIdx.x * blockDim.x + threadIdx.x; i < E; i += gridDim.x * blockDim.x) {
    const int p = atomicAdd(cursor + edge_obj[i], 1);
    ss[p] = edge_sub[i];
    srq[p] = (edge_rel[i] << 9) | q_rel[r_idx[i]];
  }
}

// ---------------------------------------------------------------------------
// Per-node gather-reduce, bf16. One wave per node; 4 edges x 16 lanes.
// ---------------------------------------------------------------------------
__global__ __launch_bounds__(256) void reduce_bf16(
    const int* __restrict__ ss, const int* __restrict__ srq,
    const int* __restrict__ offs, const short* __restrict__ Hcat,
    const short* __restrict__ Rcat, const short* __restrict__ Rwqrt,
    const float* __restrict__ wa_w, const float* __restrict__ wa_b_p,
    float* __restrict__ agg, int n_node) {
  const int node = (blockIdx.x * blockDim.x + threadIdx.x) >> 6;
  if (node >= n_node) return;
  const int l = threadIdx.x & 63;
  const int g = l >> 4;
  const int d0 = (l & 15) * 8;

  float wa8[8];
  *(float4*)(wa8) = *(const float4*)(wa_w + d0);
  *(float4*)(wa8 + 4) = *(const float4*)(wa_w + d0 + 4);
  const float wab = wa_b_p[0];

  const int start = offs[node], end = offs[node + 1];
  float acc[8];
#pragma unroll
  for (int i = 0; i < 8; ++i) acc[i] = 0.0f;

  for (int base = start; base < end; base += 64) {
    const int cnt = min(end - base, 64);
    int s_all = 0, rq_all = 0;
    if (l < cnt) { s_all = ss[base + l]; rq_all = srq[base + l]; }
    for (int c = 0; c < cnt; c += 4) {
      const int src = c + g;
      const bool valid = src < cnt;
      const int sv = __shfl(s_all, src);
      const int rqv = __shfl(rq_all, src);
      const int rv = rqv >> 9, qv = rqv & 511;

      const bf16x8 hws = *(const bf16x8*)(Hcat + ((size_t)sv << 8) + 128 + d0);
      const bf16x8 rwr = *(const bf16x8*)(Rcat + ((size_t)rv << 8) + 128 + d0);
      const bf16x8 rqr = *(const bf16x8*)(Rwqrt + ((size_t)qv << 7) + d0);
      const bf16x8 hs = *(const bf16x8*)(Hcat + ((size_t)sv << 8) + d0);
      const bf16x8 hr = *(const bf16x8*)(Rcat + ((size_t)rv << 8) + d0);

      const unsigned int* uw = (const unsigned int*)&hws;
      const unsigned int* ur = (const unsigned int*)&rwr;
      const unsigned int* uq = (const unsigned int*)&rqr;
      const unsigned int* uh = (const unsigned int*)&hs;
      const unsigned int* ug = (const unsigned int*)&hr;

      float part = 0.0f;
      float hsf[8], hrf[8];
#pragma unroll
      for (int i = 0; i < 4; ++i) {
        const float p0 = fmaxf(bflo(uw[i]) + bflo(ur[i]) + bflo(uq[i]), 0.0f);
        const float p1 = fmaxf(bfhi(uw[i]) + bfhi(ur[i]) + bfhi(uq[i]), 0.0f);
        part += p0 * wa8[2 * i] + p1 * wa8[2 * i + 1];
        hsf[2 * i] = bflo(uh[i]); hsf[2 * i + 1] = bfhi(uh[i]);
        hrf[2 * i] = bflo(ug[i]); hrf[2 * i + 1] = bfhi(ug[i]);
      }
      part += __shfl_xor(part, 1);
      part += __shfl_xor(part, 2);
      part += __shfl_xor(part, 4);
      part += __shfl_xor(part, 8);
      const float alpha = 1.0f / (1.0f + __expf(-(part + wab)));
      if (valid) {
#pragma unroll
        for (int i = 0; i < 8; ++i) acc[i] += alpha * hsf[i] * hrf[i];
      }
    }
  }
#pragma unroll
  for (int i = 0; i < 8; ++i) {
    acc[i] += __shfl_xor(acc[i], 16);
    acc[i] += __shfl_xor(acc[i], 32);
  }
  if (l < 16) {
    float4 o0 = make_float4(acc[0], acc[1], acc[2], acc[3]);
    float4 o1 = make_float4(acc[4], acc[5], acc[6], acc[7]);
    *(float4*)(agg + (size_t)node * 128 + d0) = o0;
    *(float4*)(agg + (size_t)node * 128 + d0 + 4) = o1;
  }
}

// ---------------------------------------------------------------------------
extern "C" void kernel_launch(void* const* d_in, const int* in_sizes, int n_in,
                              void* d_out, int out_size, void* d_ws, size_t ws_size,
                              hipStream_t stream) {
  const int* q_rel = (const int*)d_in[1];
  const int* r_idx = (const int*)d_in[2];
  const float* hidden = (const float*)d_in[3];
  const int* edge_sub = (const int*)d_in[4];
  const int* edge_rel = (const int*)d_in[5];
  const int* edge_obj = (const int*)d_in[6];
  const float* rela = (const float*)d_in[8];
  const float* Ws = (const float*)d_in[9];
  const float* Wr = (const float*)d_in[10];
  const float* Wqr_w = (const float*)d_in[11];
  const float* Wqr_b = (const float*)d_in[12];
  const float* wa_w = (const float*)d_in[13];
  const float* wa_b = (const float*)d_in[14];
  const float* Wh = (const float*)d_in[15];

  const int E = in_sizes[2];
  const int n_node = in_sizes[3] / 128;
  const int n_rel = in_sizes[8] / 128;
  float* out = (float*)d_out;

  auto al = [](size_t x) { return (x + 511) & ~(size_t)511; };
  char* ws = (char*)d_ws;
  size_t o = 0;
  short* Hcat = (short*)(ws + o);  o += al((size_t)n_node * 256 * 2);
  float* agg  = (float*)(ws + o);  o += al((size_t)n_node * 128 * 4);
  short* Rcat = (short*)(ws + o);  o += al((size_t)n_rel * 256 * 2);
  short* Rwqrt = (short*)(ws + o); o += al((size_t)n_rel * 128 * 2);
  short* Wst8 = (short*)(ws + o);  o += al(16384 * 2);
  short* Wrt8 = (short*)(ws + o);  o += al(16384 * 2);
  short* Wqrt8 = (short*)(ws + o); o += al(16384 * 2);
  short* Wht8 = (short*)(ws + o);  o += al(16384 * 2);
  int* deg = (int*)(ws + o);       o += al((size_t)n_node * 4);
  int* offs = (int*)(ws + o);      o += al((size_t)(n_node + 1) * 4);
  int* curs = (int*)(ws + o);      o += al((size_t)n_node * 4);
  int* bsum = (int*)(ws + o);      o += al(1024 * 4);
  int* bbase = (int*)(ws + o);     o += al(1024 * 4);
  int* ss = (int*)(ws + o);        o += al((size_t)E * 4);
  int* srq = (int*)(ws + o);       o += al((size_t)E * 4);

  // --- counting sort (hierarchical scan) ---
  hipMemsetAsync(deg, 0, (size_t)n_node * 4, stream);
  hist_kernel<<<dim3(1024), dim3(256), 0, stream>>>(edge_obj, deg, E);
  const int nb = (n_node + 511) / 512;
  scan_pass1<<<dim3(nb), dim3(256), 0, stream>>>(deg, bsum, n_node);
  scan_pass2<<<dim3(1), dim3(1024), 0, stream>>>(bsum, bbase, offs, nb, n_node);
  scan_pass3<<<dim3(nb), dim3(256), 0, stream>>>(deg, bbase, offs, curs, n_node);
  scatter_kernel<<<dim3(1024), dim3(256), 0, stream>>>(
      edge_obj, edge_sub, edge_rel, r_idx, q_rel, curs, ss, srq, E);

  // --- bf16 conversions ---
  conv_w<<<dim3(256), dim3(256), 0, stream>>>(Ws, Wr, Wqr_w, Wh,
                                              Wst8, Wrt8, Wqrt8, Wht8);
  conv_rows<<<dim3(64), dim3(256), 0, stream>>>(rela, Rcat, n_rel, 256);
  conv_rows<<<dim3(2048), dim3(256), 0, stream>>>(hidden, Hcat, n_node, 256);

  // --- projections via MFMA ---
  const int rel_blocks = (n_rel + 63) / 64;
  const int node_blocks = (n_node + 63) / 64;
  gemm_mfma<true, true, false><<<dim3(rel_blocks), dim3(256), 0, stream>>>(
      Rcat, 256, Wrt8, nullptr, Rcat, 256, 128, n_rel);
  gemm_mfma<true, true, true><<<dim3(rel_blocks), dim3(256), 0, stream>>>(
      Rcat, 256, Wqrt8, Wqr_b, Rwqrt, 128, 0, n_rel);
  gemm_mfma<true, true, false><<<dim3(node_blocks), dim3(256), 0, stream>>>(
      Hcat, 256, Wst8, nullptr, Hcat, 256, 128, n_node);

  // --- fused attention + aggregation ---
  const int rblocks = (n_node * 64 + 255) / 256;
  reduce_bf16<<<dim3(rblocks), dim3(256), 0, stream>>>(
      ss, srq, offs, Hcat, Rcat, Rwqrt, wa_w, wa_b, agg, n_node);

  // --- final projection (A f32 converted in-register) ---
  gemm_mfma<false, false, false><<<dim3(node_blocks), dim3(256), 0, stream>>>(
      agg, 128, Wht8, nullptr, out, 128, 0, n_node);
}

// Round 8
// 259.286 us; speedup vs baseline: 2.9268x; 1.0592x over previous
//
#include <hip/hip_runtime.h>

typedef float f32x4 __attribute__((ext_vector_type(4)));
typedef _Float16 f16x8 __attribute__((ext_vector_type(8)));
typedef _Float16 v2h __attribute__((ext_vector_type(2)));
typedef short s16x2 __attribute__((ext_vector_type(2)));

__device__ __forceinline__ float hdot2(v2h a, v2h b, float c) {
#if __has_builtin(__builtin_amdgcn_fdot2)
  return __builtin_amdgcn_fdot2(a, b, c, false);
#else
  return c + (float)a[0] * (float)b[0] + (float)a[1] * (float)b[1];
#endif
}

__device__ __forceinline__ v2h relu2(v2h a) {
#if __has_builtin(__builtin_elementwise_max)
  const v2h z = {(_Float16)0, (_Float16)0};
  return __builtin_elementwise_max(a, z);
#else
  const v2h z = {(_Float16)0, (_Float16)0};
  s16x2 m = a > z;                 // -1 where a>0, else 0
  s16x2 bits = *(s16x2*)&a;
  s16x2 r = bits & m;
  return *(v2h*)&r;
#endif
}

// ---------------------------------------------------------------------------
// Weight prep: 4x f32[128][128] -> fp16 transposed+k-grouped
//   Wt8[(k>>3)*1024 + col*8 + (k&7)]
// plus rela f32[475][128] -> Rcat low half fp16 (ld 256).
// ---------------------------------------------------------------------------
__global__ __launch_bounds__(256) void conv_wr(
    const float* __restrict__ W0, const float* __restrict__ W1,
    const float* __restrict__ W2, const float* __restrict__ W3,
    _Float16* __restrict__ o0, _Float16* __restrict__ o1,
    _Float16* __restrict__ o2, _Float16* __restrict__ o3,
    const float* __restrict__ rela, _Float16* __restrict__ Rcat, int n_rel) {
  const int id = blockIdx.x * 256 + threadIdx.x;
  if (id < 65536) {
    const int m = id >> 14, e = id & 16383;
    const int k = e >> 7, c = e & 127;
    const float* W = (m == 0) ? W0 : (m == 1) ? W1 : (m == 2) ? W2 : W3;
    _Float16* o = (m == 0) ? o0 : (m == 1) ? o1 : (m == 2) ? o2 : o3;
    o[(k >> 3) * 1024 + c * 8 + (k & 7)] = (_Float16)W[e];
  } else {
    const int rid = id - 65536;
    if (rid < n_rel * 128)
      Rcat[(size_t)(rid >> 7) * 256 + (rid & 127)] = (_Float16)rela[rid];
  }
}

// ---------------------------------------------------------------------------
// Dual relation GEMM (one dispatch): blocks [0,rb) -> Rcat@Wr -> Rcat high
// half; blocks [rb,2rb) -> Rcat@Wqr + bias -> Rwqrt (ld 128).
// ---------------------------------------------------------------------------
__global__ __launch_bounds__(256) void gemm_rel_dual(
    const _Float16* __restrict__ RcatA, const _Float16* __restrict__ Wrt8,
    const _Float16* __restrict__ Wqrt8, const float* __restrict__ bias,
    _Float16* __restrict__ RcatHi, _Float16* __restrict__ Rwqrt,
    int n_rel, int rel_blocks) {
  __shared__ _Float16 sW[16384];
  const bool second = (int)blockIdx.x >= rel_blocks;
  const int bb = second ? blockIdx.x - rel_blocks : blockIdx.x;
  const _Float16* Wt8 = second ? Wqrt8 : Wrt8;
  for (int i = threadIdx.x; i < 2048; i += 256)
    ((f32x4*)sW)[i] = ((const f32x4*)Wt8)[i];
  __syncthreads();

  const int wv = threadIdx.x >> 6, l = threadIdx.x & 63;
  const int row = bb * 64 + wv * 16 + (l & 15);
  const int kb = (l >> 4) * 8;
  const bool rvalid = row < n_rel;

  f16x8 a[4];
#pragma unroll
  for (int kk = 0; kk < 4; ++kk) {
    f16x8 t = {0, 0, 0, 0, 0, 0, 0, 0};
    if (rvalid) t = *(const f16x8*)(RcatA + (size_t)row * 256 + kb + 32 * kk);
    a[kk] = t;
  }

  f32x4 acc[8];
#pragma unroll
  for (int n = 0; n < 8; ++n) acc[n] = (f32x4){0.f, 0.f, 0.f, 0.f};
#pragma unroll
  for (int n = 0; n < 8; ++n)
#pragma unroll
    for (int kk = 0; kk < 4; ++kk) {
      const int kg = 4 * kk + (l >> 4);
      const f16x8 b = *(const f16x8*)(sW + kg * 1024 + (16 * n + (l & 15)) * 8);
      acc[n] = __builtin_amdgcn_mfma_f32_16x16x32_f16(a[kk], b, acc[n], 0, 0, 0);
    }

  const int orow_base = bb * 64 + wv * 16 + (l >> 4) * 4;
#pragma unroll
  for (int n = 0; n < 8; ++n) {
    const int col = 16 * n + (l & 15);
    const float badd = second ? bias[col] : 0.0f;
#pragma unroll
    for (int r4 = 0; r4 < 4; ++r4) {
      const int orow = orow_base + r4;
      if (orow < n_rel) {
        const float v = acc[n][r4] + badd;
        if (second) Rwqrt[(size_t)orow * 128 + col] = (_Float16)v;
        else        RcatHi[(size_t)orow * 256 + 128 + col] = (_Float16)v;
      }
    }
  }
}

// ---------------------------------------------------------------------------
// Fused: hidden f32 -> fp16 (Hcat low half) AND hidden@Ws -> Hcat high half.
// ---------------------------------------------------------------------------
__global__ __launch_bounds__(256) void gemm_hidden(
    const float* __restrict__ hidden, const _Float16* __restrict__ Wst8,
    _Float16* __restrict__ Hcat, int M) {
  __shared__ _Float16 sW[16384];
  for (int i = threadIdx.x; i < 2048; i += 256)
    ((f32x4*)sW)[i] = ((const f32x4*)Wst8)[i];
  __syncthreads();

  const int wv = threadIdx.x >> 6, l = threadIdx.x & 63;
  const int row = blockIdx.x * 64 + wv * 16 + (l & 15);
  const int kb = (l >> 4) * 8;
  const bool rvalid = row < M;

  f16x8 a[4];
#pragma unroll
  for (int kk = 0; kk < 4; ++kk) {
    f16x8 t = {0, 0, 0, 0, 0, 0, 0, 0};
    if (rvalid) {
      const f32x4 lo = *(const f32x4*)(hidden + (size_t)row * 128 + kb + 32 * kk);
      const f32x4 hi = *(const f32x4*)(hidden + (size_t)row * 128 + kb + 32 * kk + 4);
      t[0] = (_Float16)lo[0]; t[1] = (_Float16)lo[1];
      t[2] = (_Float16)lo[2]; t[3] = (_Float16)lo[3];
      t[4] = (_Float16)hi[0]; t[5] = (_Float16)hi[1];
      t[6] = (_Float16)hi[2]; t[7] = (_Float16)hi[3];
      *(f16x8*)(Hcat + (size_t)row * 256 + kb + 32 * kk) = t;  // low half
    }
    a[kk] = t;
  }

  f32x4 acc[8];
#pragma unroll
  for (int n = 0; n < 8; ++n) acc[n] = (f32x4){0.f, 0.f, 0.f, 0.f};
#pragma unroll
  for (int n = 0; n < 8; ++n)
#pragma unroll
    for (int kk = 0; kk < 4; ++kk) {
      const int kg = 4 * kk + (l >> 4);
      const f16x8 b = *(const f16x8*)(sW + kg * 1024 + (16 * n + (l & 15)) * 8);
      acc[n] = __builtin_amdgcn_mfma_f32_16x16x32_f16(a[kk], b, acc[n], 0, 0, 0);
    }

  const int orow_base = blockIdx.x * 64 + wv * 16 + (l >> 4) * 4;
#pragma unroll
  for (int n = 0; n < 8; ++n) {
    const int col = 16 * n + (l & 15);
#pragma unroll
    for (int r4 = 0; r4 < 4; ++r4) {
      const int orow = orow_base + r4;
      if (orow < M)
        Hcat[(size_t)orow * 256 + 128 + col] = (_Float16)acc[n][r4];
    }
  }
}

// ---------------------------------------------------------------------------
// Final projection: out[M,128] f32 = agg fp16 @ Wh.
// ---------------------------------------------------------------------------
__global__ __launch_bounds__(256) void gemm_final(
    const _Float16* __restrict__ agg, const _Float16* __restrict__ Wht8,
    float* __restrict__ out, int M) {
  __shared__ _Float16 sW[16384];
  for (int i = threadIdx.x; i < 2048; i += 256)
    ((f32x4*)sW)[i] = ((const f32x4*)Wht8)[i];
  __syncthreads();

  const int wv = threadIdx.x >> 6, l = threadIdx.x & 63;
  const int row = blockIdx.x * 64 + wv * 16 + (l & 15);
  const int kb = (l >> 4) * 8;
  const bool rvalid = row < M;

  f16x8 a[4];
#pragma unroll
  for (int kk = 0; kk < 4; ++kk) {
    f16x8 t = {0, 0, 0, 0, 0, 0, 0, 0};
    if (rvalid) t = *(const f16x8*)(agg + (size_t)row * 128 + kb + 32 * kk);
    a[kk] = t;
  }

  f32x4 acc[8];
#pragma unroll
  for (int n = 0; n < 8; ++n) acc[n] = (f32x4){0.f, 0.f, 0.f, 0.f};
#pragma unroll
  for (int n = 0; n < 8; ++n)
#pragma unroll
    for (int kk = 0; kk < 4; ++kk) {
      const int kg = 4 * kk + (l >> 4);
      const f16x8 b = *(const f16x8*)(sW + kg * 1024 + (16 * n + (l & 15)) * 8);
      acc[n] = __builtin_amdgcn_mfma_f32_16x16x32_f16(a[kk], b, acc[n], 0, 0, 0);
    }

  const int orow_base = blockIdx.x * 64 + wv * 16 + (l >> 4) * 4;
#pragma unroll
  for (int n = 0; n < 8; ++n) {
    const int col = 16 * n + (l & 15);
#pragma unroll
    for (int r4 = 0; r4 < 4; ++r4) {
      const int orow = orow_base + r4;
      if (orow < M) out[(size_t)orow * 128 + col] = acc[n][r4];
    }
  }
}

// ---------------------------------------------------------------------------
// Counting sort by edge_obj; hierarchical 3-pass scan; int2 payload scatter.
// ---------------------------------------------------------------------------
__global__ __launch_bounds__(256) void hist_kernel(const int* __restrict__ edge_obj,
                                                   int* __restrict__ deg, int E) {
  for (int i = blockIdx.x * blockDim.x + threadIdx.x; i < E; i += gridDim.x * blockDim.x)
    atomicAdd(deg + edge_obj[i], 1);
}

__global__ __launch_bounds__(256) void scan_pass1(const int* __restrict__ deg,
                                                  int* __restrict__ bsum, int n) {
  const int b = blockIdx.x, t = threadIdx.x;
  const int i0 = b * 512 + t, i1 = i0 + 256;
  int v = 0;
  if (i0 < n) v += deg[i0];
  if (i1 < n) v += deg[i1];
  __shared__ int s[256];
  s[t] = v;
  __syncthreads();
  for (int o = 128; o > 0; o >>= 1) {
    if (t < o) s[t] += s[t + o];
    __syncthreads();
  }
  if (t == 0) bsum[b] = s[0];
}

__global__ __launch_bounds__(1024) void scan_pass2(const int* __restrict__ bsum,
                                                   int* __restrict__ bbase,
                                                   int* __restrict__ off,
                                                   int nb, int n) {
  const int t = threadIdx.x;
  __shared__ int s[1024];
  const int v = (t < nb) ? bsum[t] : 0;
  s[t] = v;
  __syncthreads();
  for (int o = 1; o < 1024; o <<= 1) {
    const int a = (t >= o) ? s[t - o] : 0;
    __syncthreads();
    s[t] += a;
    __syncthreads();
  }
  if (t < nb) bbase[t] = s[t] - v;
  if (t == 1023) off[n] = s[1023];
}

__global__ __launch_bounds__(256) void scan_pass3(const int* __restrict__ deg,
                                                  const int* __restrict__ bbase,
                                                  int* __restrict__ off,
                                                  int* __restrict__ cursor, int n) {
  const int b = blockIdx.x, t = threadIdx.x;
  const int i0 = b * 512 + t, i1 = i0 + 256;
  const int d0 = (i0 < n) ? deg[i0] : 0;
  const int d1 = (i1 < n) ? deg[i1] : 0;
  __shared__ int s[512];
  s[t] = d0;
  s[t + 256] = d1;
  __syncthreads();
  for (int o = 1; o < 512; o <<= 1) {
    const int a0 = (t >= o) ? s[t - o] : 0;
    const int a1 = (t + 256 >= o) ? s[t + 256 - o] : 0;
    __syncthreads();
    s[t] += a0;
    s[t + 256] += a1;
    __syncthreads();
  }
  const int base = bbase[b];
  if (i0 < n) { const int e = base + s[t] - d0;       off[i0] = e; cursor[i0] = e; }
  if (i1 < n) { const int e = base + s[t + 256] - d1; off[i1] = e; cursor[i1] = e; }
}

__global__ __launch_bounds__(256) void scatter_kernel(
    const int* __restrict__ edge_obj, const int* __restrict__ edge_sub,
    const int* __restrict__ edge_rel, const int* __restrict__ r_idx,
    const int* __restrict__ q_rel, int* __restrict__ cursor,
    int2* __restrict__ ssrq, int E) {
  for (int i = blockIdx.x * blockDim.x + threadIdx.x; i < E; i += gridDim.x * blockDim.x) {
    const int p = atomicAdd(cursor + edge_obj[i], 1);
    ssrq[p] = make_int2(edge_sub[i], (edge_rel[i] << 9) | q_rel[r_idx[i]]);
  }
}

// ---------------------------------------------------------------------------
// Per-node gather-reduce, fp16 packed math (native v2h ops). One wave per
// node; 4 edges x 16 lanes; lane owns dims [8*(l&15), +8). agg fp16 (ld 128).
// ---------------------------------------------------------------------------
__global__ __launch_bounds__(256) void reduce_f16(
    const int2* __restrict__ ssrq, const int* __restrict__ offs,
    const _Float16* __restrict__ Hcat, const _Float16* __restrict__ Rcat,
    const _Float16* __restrict__ Rwqrt, const float* __restrict__ wa_w,
    const float* __restrict__ wa_b_p, _Float16* __restrict__ agg, int n_node) {
  const int node = (blockIdx.x * blockDim.x + threadIdx.x) >> 6;
  if (node >= n_node) return;
  const int l = threadIdx.x & 63;
  const int g = l >> 4;
  const int d0 = (l & 15) * 8;

  v2h wa2[4];
  {
    const float4 w0 = *(const float4*)(wa_w + d0);
    const float4 w1 = *(const float4*)(wa_w + d0 + 4);
    wa2[0] = (v2h){(_Float16)w0.x, (_Float16)w0.y};
    wa2[1] = (v2h){(_Float16)w0.z, (_Float16)w0.w};
    wa2[2] = (v2h){(_Float16)w1.x, (_Float16)w1.y};
    wa2[3] = (v2h){(_Float16)w1.z, (_Float16)w1.w};
  }
  const float wab = wa_b_p[0];

  const int start = offs[node], end = offs[node + 1];
  v2h acc2[4] = {};

  for (int base = start; base < end; base += 64) {
    const int cnt = min(end - base, 64);
    int s_all = 0, rq_all = 0;
    if (l < cnt) { const int2 sr = ssrq[base + l]; s_all = sr.x; rq_all = sr.y; }
    for (int c = 0; c < cnt; c += 4) {
      const int src = c + g;
      const bool valid = src < cnt;
      const int sv = __shfl(s_all, src);
      const int rqv = __shfl(rq_all, src);
      const int rv = rqv >> 9, qv = rqv & 511;

      f32x4 rw = *(const f32x4*)(Hcat + ((size_t)sv << 8) + 128 + d0);
      f32x4 rr = *(const f32x4*)(Rcat + ((size_t)rv << 8) + 128 + d0);
      f32x4 rq = *(const f32x4*)(Rwqrt + ((size_t)qv << 7) + d0);
      f32x4 rh = *(const f32x4*)(Hcat + ((size_t)sv << 8) + d0);
      f32x4 rg = *(const f32x4*)(Rcat + ((size_t)rv << 8) + d0);
      const v2h* hw = (const v2h*)&rw;
      const v2h* hr_ = (const v2h*)&rr;
      const v2h* hq = (const v2h*)&rq;
      const v2h* hh = (const v2h*)&rh;
      const v2h* hg = (const v2h*)&rg;

      float part = 0.0f;
      v2h prod[4];
#pragma unroll
      for (int i = 0; i < 4; ++i) {
        const v2h pre = relu2(hw[i] + hr_[i] + hq[i]);
        part = hdot2(pre, wa2[i], part);
        prod[i] = hh[i] * hg[i];
      }
      part += __shfl_xor(part, 1);
      part += __shfl_xor(part, 2);
      part += __shfl_xor(part, 4);
      part += __shfl_xor(part, 8);
      const float alpha = valid ? 1.0f / (1.0f + __expf(-(part + wab))) : 0.0f;
      const _Float16 ah = (_Float16)alpha;
      const v2h alpha2 = {ah, ah};
#pragma unroll
      for (int i = 0; i < 4; ++i) acc2[i] += alpha2 * prod[i];
    }
  }

#pragma unroll
  for (int i = 0; i < 4; ++i) {
    unsigned x = *(unsigned*)&acc2[i];
    unsigned y = (unsigned)__shfl_xor((int)x, 16);
    acc2[i] += *(v2h*)&y;
    x = *(unsigned*)&acc2[i];
    y = (unsigned)__shfl_xor((int)x, 32);
    acc2[i] += *(v2h*)&y;
  }
  if (l < 16)
    *(f32x4*)(agg + (size_t)node * 128 + d0) = *(f32x4*)acc2;
}

// ---------------------------------------------------------------------------
extern "C" void kernel_launch(void* const* d_in, const int* in_sizes, int n_in,
                              void* d_out, int out_size, void* d_ws, size_t ws_size,
                              hipStream_t stream) {
  const int* q_rel = (const int*)d_in[1];
  const int* r_idx = (const int*)d_in[2];
  const float* hidden = (const float*)d_in[3];
  const int* edge_sub = (const int*)d_in[4];
  const int* edge_rel = (const int*)d_in[5];
  const int* edge_obj = (const int*)d_in[6];
  const float* rela = (const float*)d_in[8];
  const float* Ws = (const float*)d_in[9];
  const float* Wr = (const float*)d_in[10];
  const float* Wqr_w = (const float*)d_in[11];
  const float* Wqr_b = (const float*)d_in[12];
  const float* wa_w = (const float*)d_in[13];
  const float* wa_b = (const float*)d_in[14];
  const float* Wh = (const float*)d_in[15];

  const int E = in_sizes[2];
  const int n_node = in_sizes[3] / 128;
  const int n_rel = in_sizes[8] / 128;
  float* out = (float*)d_out;

  auto al = [](size_t x) { return (x + 511) & ~(size_t)511; };
  char* ws = (char*)d_ws;
  size_t o = 0;
  _Float16* Hcat = (_Float16*)(ws + o);  o += al((size_t)n_node * 256 * 2);
  _Float16* agg  = (_Float16*)(ws + o);  o += al((size_t)n_node * 128 * 2);
  _Float16* Rcat = (_Float16*)(ws + o);  o += al((size_t)n_rel * 256 * 2);
  _Float16* Rwqrt = (_Float16*)(ws + o); o += al((size_t)n_rel * 128 * 2);
  _Float16* Wst8 = (_Float16*)(ws + o);  o += al(16384 * 2);
  _Float16* Wrt8 = (_Float16*)(ws + o);  o += al(16384 * 2);
  _Float16* Wqrt8 = (_Float16*)(ws + o); o += al(16384 * 2);
  _Float16* Wht8 = (_Float16*)(ws + o);  o += al(16384 * 2);
  int* deg = (int*)(ws + o);       o += al((size_t)n_node * 4);
  int* offs = (int*)(ws + o);      o += al((size_t)(n_node + 1) * 4);
  int* curs = (int*)(ws + o);      o += al((size_t)n_node * 4);
  int* bsum = (int*)(ws + o);      o += al(1024 * 4);
  int* bbase = (int*)(ws + o);     o += al(1024 * 4);
  int2* ssrq = (int2*)(ws + o);    o += al((size_t)E * 8);

  // --- counting sort (hierarchical scan, int2 payload) ---
  (void)hipMemsetAsync(deg, 0, (size_t)n_node * 4, stream);
  hist_kernel<<<dim3(1024), dim3(256), 0, stream>>>(edge_obj, deg, E);
  const int nb = (n_node + 511) / 512;
  scan_pass1<<<dim3(nb), dim3(256), 0, stream>>>(deg, bsum, n_node);
  scan_pass2<<<dim3(1), dim3(1024), 0, stream>>>(bsum, bbase, offs, nb, n_node);
  scan_pass3<<<dim3(nb), dim3(256), 0, stream>>>(deg, bbase, offs, curs, n_node);
  scatter_kernel<<<dim3(1024), dim3(256), 0, stream>>>(
      edge_obj, edge_sub, edge_rel, r_idx, q_rel, curs, ssrq, E);

  // --- fp16 weight/relation prep (one dispatch) ---
  const int prep_ids = 65536 + n_rel * 128;
  conv_wr<<<dim3((prep_ids + 255) / 256), dim3(256), 0, stream>>>(
      Ws, Wr, Wqr_w, Wh, Wst8, Wrt8, Wqrt8, Wht8, rela, Rcat, n_rel);

  // --- relation projections (one dual dispatch) ---
  const int rel_blocks = (n_rel + 63) / 64;
  gemm_rel_dual<<<dim3(rel_blocks * 2), dim3(256), 0, stream>>>(
      Rcat, Wrt8, Wqrt8, Wqr_b, Rcat, Rwqrt, n_rel, rel_blocks);

  // --- fused hidden conversion + Ws projection ---
  const int node_blocks = (n_node + 63) / 64;
  gemm_hidden<<<dim3(node_blocks), dim3(256), 0, stream>>>(hidden, Wst8, Hcat, n_node);

  // --- fused attention + aggregation ---
  const int rblocks = (n_node * 64 + 255) / 256;
  reduce_f16<<<dim3(rblocks), dim3(256), 0, stream>>>(
      ssrq, offs, Hcat, Rcat, Rwqrt, wa_w, wa_b, agg, n_node);

  // --- final projection ---
  gemm_final<<<dim3(node_blocks), dim3(256), 0, stream>>>(agg, Wht8, out, n_node);
}